// Round 8
// baseline (192.256 us; speedup 1.0000x reference)
//
#include <hip/hip_runtime.h>

// FK chain, LDS-transpose writer (r7 structure + non-temporal output stores).
// - block = 1 wave (64 lanes) = 1 group of 64 elements; no cross-iteration
//   LDS reuse (race-free by construction).
// - Stage rows 0-2 of each frame (row 3 = (0,0,0,1) synthesized at flush):
//   24 float4/lane, LSTRIDE 25 -> 25.6 KB -> 6 blocks/CU.
// - Flush: 32 fully-contiguous 1 KB wave stores (dense 32 KB span),
//   lane-constant LDS addressing, __builtin_nontemporal_store (nt flag:
//   streaming writes, no L2 temporal reuse).

#define LSTRIDE 25  // 24 payload float4 + 1 pad

typedef float f32x4 __attribute__((ext_vector_type(4)));

namespace {

struct V3 { float x, y, z; };
__device__ __forceinline__ V3 v3(float x, float y, float z) { return {x, y, z}; }

__device__ __forceinline__ void stage3(f32x4* p, V3 c0, V3 c1, V3 c2, V3 c3) {
    p[0] = (f32x4){c0.x, c1.x, c2.x, c3.x};
    p[1] = (f32x4){c0.y, c1.y, c2.y, c3.y};
    p[2] = (f32x4){c0.z, c1.z, c2.z, c3.z};
}

} // namespace

__global__ __launch_bounds__(64) void fk_chain_kernel(const float* __restrict__ q,
                                                      f32x4* __restrict__ out,
                                                      int n)
{
    __shared__ f32x4 lds[64 * LSTRIDE];  // 25,600 B

    const int lane = threadIdx.x;                     // block == 1 wave
    const long long e0 = (long long)blockIdx.x * 64;  // group's first element
    long long i = e0 + lane;
    if (i >= n) i = n - 1;                            // clamp; stores guarded

    const float* qi = q + i * 7;
    const float HPI = 1.57079632679489662f;

    float qv[7];
    #pragma unroll
    for (int k = 0; k < 7; ++k) qv[k] = qi[k];

    float c[7], s[7];
    __sincosf(qv[0], &s[0], &c[0]);
    __sincosf(qv[1], &s[1], &c[1]);
    __sincosf(qv[2] - HPI, &s[2], &c[2]);
    __sincosf(qv[3], &s[3], &c[3]);
    __sincosf(qv[4], &s[4], &c[4]);
    __sincosf(qv[5] + HPI, &s[5], &c[5]);
    __sincosf(qv[6] - HPI, &s[6], &c[6]);

    f32x4* myS = lds + lane * LSTRIDE;

    // chain state: columns of current frame (bottom row implicit)
    V3 f0 = v3(c[0], s[0], 0.f);
    V3 f1 = v3(-s[0], c[0], 0.f);
    V3 f2 = v3(0.f, 0.f, 1.f);
    V3 f3 = v3(0.f, 0.f, 0.f);

    #define TYPE_A(cc, ss)                                              \
        {                                                               \
            V3 t0 = v3((cc)*f0.x + (ss)*f2.x, (cc)*f0.y + (ss)*f2.y, (cc)*f0.z + (ss)*f2.z); \
            V3 t1 = v3((cc)*f2.x - (ss)*f0.x, (cc)*f2.y - (ss)*f0.y, (cc)*f2.z - (ss)*f0.z); \
            V3 t2 = v3(-f1.x, -f1.y, -f1.z);                            \
            f0 = t0; f1 = t1; f2 = t2;                                  \
        }

    stage3(myS + 0, f0, f1, f2, f3);                     // frame 0 = m0

    TYPE_A(c[1], s[1]);                                  // m1
    stage3(myS + 3, f0, f1, f2, f3);

    // m2: f0' = c*f0 - s*f2; f1' = -(s*f0 + c*f2); f2' = f1; f3 += 0.4*f1
    {
        V3 t0 = v3(c[2]*f0.x - s[2]*f2.x, c[2]*f0.y - s[2]*f2.y, c[2]*f0.z - s[2]*f2.z);
        V3 t1 = v3(-(s[2]*f0.x + c[2]*f2.x), -(s[2]*f0.y + c[2]*f2.y), -(s[2]*f0.z + c[2]*f2.z));
        V3 t2 = f1;
        f3 = v3(0.4f*f1.x + f3.x, 0.4f*f1.y + f3.y, 0.4f*f1.z + f3.z);
        f0 = t0; f1 = t1; f2 = t2;
    }
    stage3(myS + 6, f0, f1, f2, f3);

    TYPE_A(c[3], s[3]);                                  // m3
    stage3(myS + 9, f0, f1, f2, f3);

    // m4: f0' = s*f2 - c*f0; f1' = s*f0 + c*f2; f2' = f1; f3 += 0.39*f1
    {
        V3 t0 = v3(s[4]*f2.x - c[4]*f0.x, s[4]*f2.y - c[4]*f0.y, s[4]*f2.z - c[4]*f0.z);
        V3 t1 = v3(s[4]*f0.x + c[4]*f2.x, s[4]*f0.y + c[4]*f2.y, s[4]*f0.z + c[4]*f2.z);
        V3 t2 = f1;
        f3 = v3(0.39f*f1.x + f3.x, 0.39f*f1.y + f3.y, 0.39f*f1.z + f3.z);
        f0 = t0; f1 = t1; f2 = t2;
    }
    stage3(myS + 12, f0, f1, f2, f3);

    TYPE_A(c[5], s[5]);                                  // m5
    stage3(myS + 15, f0, f1, f2, f3);

    TYPE_A(c[6], s[6]);                                  // m6
    stage3(myS + 18, f0, f1, f2, f3);

    // m7: f0' = -f0; f1' = f2; f2' = f1; f3 += 0.118*f1
    {
        V3 t0 = v3(-f0.x, -f0.y, -f0.z);
        V3 t1 = f2;
        V3 t2 = f1;
        f3 = v3(0.118f*f1.x + f3.x, 0.118f*f1.y + f3.y, 0.118f*f1.z + f3.z);
        f0 = t0; f1 = t1; f2 = t2;
    }
    stage3(myS + 21, f0, f1, f2, f3);

    #undef TYPE_A

    __syncthreads();  // order all ds_writes before cross-lane ds_reads

    // ---- flush: 32 dense 1 KB wave stores (nt) over the group's 32 KB span ----
    const int hi = lane >> 5;             // element parity within a store
    const int p  = lane & 31;
    const int fr = p >> 2;                // frame 0..7
    const int r  = p & 3;                 // row 0..3
    const int rb = hi * LSTRIDE + fr * 3 + ((r == 3) ? 2 : r);
    const bool isr3 = (r == 3);
    const f32x4 row3 = (f32x4){0.f, 0.f, 0.f, 1.f};

    f32x4* gb = out + e0 * 32;            // 64 elem * 32 float4
    if (e0 + 64 <= (long long)n) {
        #pragma unroll
        for (int j = 0; j < 32; ++j) {
            f32x4 v = lds[j * (2 * LSTRIDE) + rb];
            if (isr3) v = row3;
            __builtin_nontemporal_store(v, &gb[j * 64 + lane]);
        }
    } else {
        #pragma unroll
        for (int j = 0; j < 32; ++j) {
            f32x4 v = lds[j * (2 * LSTRIDE) + rb];
            if (isr3) v = row3;
            if (e0 + (j * 2 + hi) < (long long)n)
                __builtin_nontemporal_store(v, &gb[j * 64 + lane]);
        }
    }
}

extern "C" void kernel_launch(void* const* d_in, const int* in_sizes, int n_in,
                              void* d_out, int out_size, void* d_ws, size_t ws_size,
                              hipStream_t stream) {
    const float* x = (const float*)d_in[0];
    f32x4* out = (f32x4*)d_out;
    int n = in_sizes[0] / 7;            // 2,000,000 elements
    int grid = (n + 63) >> 6;           // 31,250 one-wave blocks
    fk_chain_kernel<<<grid, 64, 0, stream>>>(x, out, n);
}

// Round 9
// 187.933 us; speedup vs baseline: 1.0230x; 1.0230x over previous
//
#include <hip/hip_runtime.h>

// FK chain, LDS-transpose writer (r7 structure — best measured: 187.4 us).
// - block = 1 wave (64 lanes) = 1 group of 64 elements; no cross-iteration
//   LDS reuse (race-free by construction).
// - Stage rows 0-2 of each frame (row 3 = (0,0,0,1) synthesized at flush):
//   24 float4/lane, LSTRIDE 25 -> 25.6 KB -> 6 blocks/CU.
// - Flush: 32 fully-contiguous 1 KB wave stores (dense 32 KB span),
//   lane-constant LDS addressing. Plain stores (nt was -2.6%: r8).

#define LSTRIDE 25  // 24 payload float4 + 1 pad

namespace {

struct V3 { float x, y, z; };
__device__ __forceinline__ V3 v3(float x, float y, float z) { return {x, y, z}; }

__device__ __forceinline__ void stage3(float4* p, V3 c0, V3 c1, V3 c2, V3 c3) {
    p[0] = make_float4(c0.x, c1.x, c2.x, c3.x);
    p[1] = make_float4(c0.y, c1.y, c2.y, c3.y);
    p[2] = make_float4(c0.z, c1.z, c2.z, c3.z);
}

} // namespace

__global__ __launch_bounds__(64) void fk_chain_kernel(const float* __restrict__ q,
                                                      float4* __restrict__ out,
                                                      int n)
{
    __shared__ float4 lds[64 * LSTRIDE];  // 25,600 B

    const int lane = threadIdx.x;                     // block == 1 wave
    const long long e0 = (long long)blockIdx.x * 64;  // group's first element
    long long i = e0 + lane;
    if (i >= n) i = n - 1;                            // clamp; stores guarded

    const float* qi = q + i * 7;
    const float HPI = 1.57079632679489662f;

    float qv[7];
    #pragma unroll
    for (int k = 0; k < 7; ++k) qv[k] = qi[k];

    float c[7], s[7];
    __sincosf(qv[0], &s[0], &c[0]);
    __sincosf(qv[1], &s[1], &c[1]);
    __sincosf(qv[2] - HPI, &s[2], &c[2]);
    __sincosf(qv[3], &s[3], &c[3]);
    __sincosf(qv[4], &s[4], &c[4]);
    __sincosf(qv[5] + HPI, &s[5], &c[5]);
    __sincosf(qv[6] - HPI, &s[6], &c[6]);

    float4* myS = lds + lane * LSTRIDE;

    // chain state: columns of current frame (bottom row implicit)
    V3 f0 = v3(c[0], s[0], 0.f);
    V3 f1 = v3(-s[0], c[0], 0.f);
    V3 f2 = v3(0.f, 0.f, 1.f);
    V3 f3 = v3(0.f, 0.f, 0.f);

    #define TYPE_A(cc, ss)                                              \
        {                                                               \
            V3 t0 = v3((cc)*f0.x + (ss)*f2.x, (cc)*f0.y + (ss)*f2.y, (cc)*f0.z + (ss)*f2.z); \
            V3 t1 = v3((cc)*f2.x - (ss)*f0.x, (cc)*f2.y - (ss)*f0.y, (cc)*f2.z - (ss)*f0.z); \
            V3 t2 = v3(-f1.x, -f1.y, -f1.z);                            \
            f0 = t0; f1 = t1; f2 = t2;                                  \
        }

    stage3(myS + 0, f0, f1, f2, f3);                     // frame 0 = m0

    TYPE_A(c[1], s[1]);                                  // m1
    stage3(myS + 3, f0, f1, f2, f3);

    // m2: f0' = c*f0 - s*f2; f1' = -(s*f0 + c*f2); f2' = f1; f3 += 0.4*f1
    {
        V3 t0 = v3(c[2]*f0.x - s[2]*f2.x, c[2]*f0.y - s[2]*f2.y, c[2]*f0.z - s[2]*f2.z);
        V3 t1 = v3(-(s[2]*f0.x + c[2]*f2.x), -(s[2]*f0.y + c[2]*f2.y), -(s[2]*f0.z + c[2]*f2.z));
        V3 t2 = f1;
        f3 = v3(0.4f*f1.x + f3.x, 0.4f*f1.y + f3.y, 0.4f*f1.z + f3.z);
        f0 = t0; f1 = t1; f2 = t2;
    }
    stage3(myS + 6, f0, f1, f2, f3);

    TYPE_A(c[3], s[3]);                                  // m3
    stage3(myS + 9, f0, f1, f2, f3);

    // m4: f0' = s*f2 - c*f0; f1' = s*f0 + c*f2; f2' = f1; f3 += 0.39*f1
    {
        V3 t0 = v3(s[4]*f2.x - c[4]*f0.x, s[4]*f2.y - c[4]*f0.y, s[4]*f2.z - c[4]*f0.z);
        V3 t1 = v3(s[4]*f0.x + c[4]*f2.x, s[4]*f0.y + c[4]*f2.y, s[4]*f0.z + c[4]*f2.z);
        V3 t2 = f1;
        f3 = v3(0.39f*f1.x + f3.x, 0.39f*f1.y + f3.y, 0.39f*f1.z + f3.z);
        f0 = t0; f1 = t1; f2 = t2;
    }
    stage3(myS + 12, f0, f1, f2, f3);

    TYPE_A(c[5], s[5]);                                  // m5
    stage3(myS + 15, f0, f1, f2, f3);

    TYPE_A(c[6], s[6]);                                  // m6
    stage3(myS + 18, f0, f1, f2, f3);

    // m7: f0' = -f0; f1' = f2; f2' = f1; f3 += 0.118*f1
    {
        V3 t0 = v3(-f0.x, -f0.y, -f0.z);
        V3 t1 = f2;
        V3 t2 = f1;
        f3 = v3(0.118f*f1.x + f3.x, 0.118f*f1.y + f3.y, 0.118f*f1.z + f3.z);
        f0 = t0; f1 = t1; f2 = t2;
    }
    stage3(myS + 21, f0, f1, f2, f3);

    #undef TYPE_A

    __syncthreads();  // order all ds_writes before cross-lane ds_reads

    // ---- flush: 32 dense 1 KB wave stores over the group's 32 KB span ----
    // Store j covers float4 span [j*64, (j+1)*64); since 64 % 32 == 0, this
    // lane's within-element float4 index p = lane & 31 is fixed across j.
    const int hi = lane >> 5;             // element parity within a store
    const int p  = lane & 31;
    const int fr = p >> 2;                // frame 0..7
    const int r  = p & 3;                 // row 0..3
    const int rb = hi * LSTRIDE + fr * 3 + ((r == 3) ? 2 : r);
    const bool isr3 = (r == 3);
    const float4 row3 = make_float4(0.f, 0.f, 0.f, 1.f);

    float4* gb = out + e0 * 32;           // 64 elem * 32 float4
    if (e0 + 64 <= (long long)n) {
        #pragma unroll
        for (int j = 0; j < 32; ++j) {
            float4 v = lds[j * (2 * LSTRIDE) + rb];
            if (isr3) v = row3;
            gb[j * 64 + lane] = v;
        }
    } else {
        #pragma unroll
        for (int j = 0; j < 32; ++j) {
            float4 v = lds[j * (2 * LSTRIDE) + rb];
            if (isr3) v = row3;
            if (e0 + (j * 2 + hi) < (long long)n)
                gb[j * 64 + lane] = v;
        }
    }
}

extern "C" void kernel_launch(void* const* d_in, const int* in_sizes, int n_in,
                              void* d_out, int out_size, void* d_ws, size_t ws_size,
                              hipStream_t stream) {
    const float* x = (const float*)d_in[0];
    float* out = (float*)d_out;
    int n = in_sizes[0] / 7;            // 2,000,000 elements
    int grid = (n + 63) >> 6;           // 31,250 one-wave blocks
    fk_chain_kernel<<<grid, 64, 0, stream>>>(x, (float4*)out, n);
}